// Round 3
// baseline (17288.818 us; speedup 1.0000x reference)
//
#include <hip/hip_runtime.h>
#include <math.h>

#define Bsz 256
#define Tsz 196
#define Fsz 263
#define Hsz 1024
#define TFs (Tsz*Fsz)   // 51548

// ---------------- ws layout (floats) ----------------
// region [0, 4194304) : precompute: WihT ; loop: hbuf(2x262144)+cbuf+partial
#define WS_HBUF    0u
#define WS_CBUF    524288u
#define WS_PART    786432u      // 32*256*263 = 2154496  (ends 2940928 < 4194304)
#define WS_WIHT    0u           // 1024*4096
#define WS_WHHT    4194304u     // 1024*4096
#define WS_LIN2T   8388608u     // 1024*263 = 269312
#define WS_LIN1T   8657920u     // 263*512  = 134656
#define WS_LTWT    8792576u     // 768*512  = 393216
#define WS_TEXTE   9185792u     // 256*512  = 131072
#define WS_WCOMB   9316864u     // 288*4096 = 1179648 (rows 263..287 zeroed)
#define WS_CONSTG  10496512u    // 256*4096 = 1048576
#define WS_BIASG   11545088u    // 4096
#define WS_TOTAL   11549184u    // 46.2 MB

// ---------------- async global->LDS ----------------
__device__ __forceinline__ void glds16(const float* g, float* l) {
    __builtin_amdgcn_global_load_lds(
        (const __attribute__((address_space(1))) void*)g,
        (__attribute__((address_space(3))) void*)l, 16, 0, 0);
}
__device__ __forceinline__ void glds4(const float* g, float* l) {
    __builtin_amdgcn_global_load_lds(
        (const __attribute__((address_space(1))) void*)g,
        (__attribute__((address_space(3))) void*)l, 4, 0, 0);
}

__device__ __forceinline__ float sigm(float x) { return 1.f / (1.f + expf(-x)); }

// ---------------- transpose: src[M][N] -> dst[N][M] ----------------
__global__ __launch_bounds__(256) void tpose(const float* __restrict__ src,
                                             float* __restrict__ dst, int M, int N) {
    __shared__ float tile[32][33];
    int bx = blockIdx.x, by = blockIdx.y;
    int tx = threadIdx.x & 31, ty = threadIdx.x >> 5; // ty 0..7
#pragma unroll
    for (int i = 0; i < 4; ++i) {
        int row = by*32 + ty*4 + i;
        int col = bx*32 + tx;
        tile[ty*4+i][tx] = (row < M && col < N) ? src[(size_t)row*N + col] : 0.f;
    }
    __syncthreads();
#pragma unroll
    for (int i = 0; i < 4; ++i) {
        int row = bx*32 + ty*4 + i;   // dst row (= src col)
        int col = by*32 + tx;         // dst col (= src row)
        if (row < N && col < M) dst[(size_t)row*M + col] = tile[tx][ty*4+i];
    }
}

// ---------------- bias_g[j] = b_ih[j]+b_hh[j]+sum_e lin1_b[e]*WihT[e][j] ----------------
__global__ __launch_bounds__(256) void biasg_k(const float* __restrict__ bih,
                                               const float* __restrict__ bhh,
                                               const float* __restrict__ l1b,
                                               const float* __restrict__ WihT,
                                               float* __restrict__ bg) {
    int j = blockIdx.x*256 + threadIdx.x;   // grid=16 -> j<4096
    float s = bih[j] + bhh[j];
    for (int e = 0; e < 512; ++e) s += l1b[e] * WihT[(size_t)e*4096 + j];
    bg[j] = s;
}

// ---------------- generic NN GEMM: C[M][N] = A[M][K] @ B[K][N] (+bias) ----------------
// N % 64 == 0, K % 32 == 0. A rows >= MA read as 0 (used to zero-pad Wcomb rows).
__global__ __launch_bounds__(256) void nn_gemm(const float* __restrict__ A,
                                               const float* __restrict__ B,
                                               const float* __restrict__ bias,
                                               float* __restrict__ C,
                                               int M, int MA, int N, int K) {
    __shared__ float As[32][33];
    __shared__ float Bs[32][64];
    int tid = threadIdx.x;
    int r0 = blockIdx.y*32, c0 = blockIdx.x*64;
    int tr = tid >> 4;    // 0..15 (2 rows each)
    int tc = tid & 15;    // 0..15 (4 cols each)
    float acc[2][4] = {};
    for (int k0 = 0; k0 < K; k0 += 32) {
        {
            int m = tid >> 3, kb = (tid & 7)*4;
            int row = r0 + m;
#pragma unroll
            for (int i = 0; i < 4; ++i) {
                float v = 0.f;
                if (row < MA) v = A[(size_t)row*K + k0 + kb + i];
                As[m][kb+i] = v;
            }
#pragma unroll
            for (int i = 0; i < 8; ++i) {
                int fi = i*256 + tid;
                int kk = fi >> 6, cc = fi & 63;
                Bs[kk][cc] = B[(size_t)(k0+kk)*N + c0 + cc];
            }
        }
        __syncthreads();
#pragma unroll
        for (int k = 0; k < 32; ++k) {
            float a0 = As[2*tr][k], a1 = As[2*tr+1][k];
            float b0 = Bs[k][4*tc+0], b1 = Bs[k][4*tc+1];
            float b2 = Bs[k][4*tc+2], b3 = Bs[k][4*tc+3];
            acc[0][0] += a0*b0; acc[0][1] += a0*b1; acc[0][2] += a0*b2; acc[0][3] += a0*b3;
            acc[1][0] += a1*b0; acc[1][1] += a1*b1; acc[1][2] += a1*b2; acc[1][3] += a1*b3;
        }
        __syncthreads();
    }
#pragma unroll
    for (int i = 0; i < 2; ++i) {
        int row = r0 + 2*tr + i;
        if (row < M) {
#pragma unroll
            for (int j = 0; j < 4; ++j) {
                int col = c0 + 4*tc + j;
                float v = acc[i][j];
                if (bias) v += bias[col];
                C[(size_t)row*N + col] = v;
            }
        }
    }
}

__global__ __launch_bounds__(256) void zero_f(float* p, int n) {
    int i = blockIdx.x*256 + threadIdx.x;
    if (i < n) p[i] = 0.f;
}

// ---------------- per-step fused kernel ----------------
// gates(256x4096) = frame(256x<=288) @ Wcomb(288x4096) + h(256x1024) @ WhhT(1024x4096) + constG
// then LSTM cell -> hOut, cSt ; then partial[ut] = hslice(32x32) @ lin2t(slice x 263)
// grid = (32 u-tiles, 8 row-tiles), 256 threads.
// A-tile in LDS is rotation-swizzled: element (m, k) stored at m*32 + ((k + 4*m) & 31)
// (swizzle applied on the GLOBAL source address; LDS dest stays linear for global_load_lds).
// Micro-tile rows are tr + 8*i so each ds_read_b128's unique addresses spread across banks.
__global__ __launch_bounds__(256) void k1_step(
        const float* __restrict__ frame, int frameStride,
        const float* __restrict__ Wcomb,     // [288][4096]
        const float* __restrict__ hIn,       // [256][1024]
        const float* __restrict__ WhhT,      // [1024][4096]
        const float* __restrict__ constG,    // [256][4096]
        float* __restrict__ cSt,             // [256][1024]
        float* __restrict__ hOut,            // [256][1024]
        const float* __restrict__ lin2t,     // [1024][263]
        float* __restrict__ partial)         // [32][256][263]
{
    __shared__ float As[2][1024];   // 32 rows x 32 k (swizzled)
    __shared__ float Bs[2][4096];   // 32 k x 128 cols (linear [k][cc])
    const int tid = threadIdx.x;
    const int ut = blockIdx.x, rt = blockIdx.y;
    const int ubase = ut*32, r0 = rt*32;
    const int tr = tid >> 5;        // 0..7
    const int tc = tid & 31;        // 0..31
    // B source column for this thread's glds16 slots (cc = 4*(tid&31))
    const int jcol = ubase + 4*(tid & 7) + 1024*((tid & 31) >> 3);
    // phase-A A-load: element k (mod 32) feeding dest slot tid&31 of row e*8+(tid>>5)
    const int kswA = ((tid & 31) - 4*(tid >> 5)) & 31;
    // phase-B A-load: dest row m = tid>>3, dest slots 4*(tid&7).. -> source k base:
    const int kswB = (4*(tid & 7) - 4*((tid >> 3) & 7)) & 31;

    float acc[4][4] = {};

    auto issueLoads = [&](int c, int buf) {
        float* AsD = &As[buf][0];
        float* BsD = &Bs[buf][0];
        if (c < 9) {                      // phase A: frame @ Wcomb (K padded to 288)
            int k0 = c*32;
            int k = k0 + kswA;
            int kc = (k < Fsz) ? k : (Fsz - 1);   // clamp; Wcomb rows>=263 are 0
#pragma unroll
            for (int e = 0; e < 4; ++e) {
                int m = e*8 + (tid >> 5);
                glds4(frame + (size_t)(r0+m)*frameStride + kc, AsD + e*256 + tid);
            }
#pragma unroll
            for (int i = 0; i < 4; ++i) {
                int row = k0 + i*8 + (tid >> 5);
                glds16(Wcomb + (size_t)row*4096 + jcol, BsD + i*1024 + tid*4);
            }
        } else {                          // phase B: h @ WhhT
            int k0 = (c-9)*32;
            glds16(hIn + (size_t)(r0 + (tid >> 3))*1024 + k0 + kswB, AsD + tid*4);
#pragma unroll
            for (int i = 0; i < 4; ++i) {
                int row = k0 + i*8 + (tid >> 5);
                glds16(WhhT + (size_t)row*4096 + jcol, BsD + i*1024 + tid*4);
            }
        }
    };

    issueLoads(0, 0);
    __syncthreads();                     // implicit vmcnt(0) drain

    for (int c = 0; c < 41; ++c) {
        if (c < 40) issueLoads(c+1, (c+1)&1);
        const float* AsC = &As[c & 1][0];
        const float* BsC = &Bs[c & 1][0];
#pragma unroll
        for (int k4 = 0; k4 < 32; k4 += 4) {
            const int sA = (k4 + 4*tr) & 31;   // rotation for rows tr+8*i (4*m mod 32 == 4*tr)
            float4 aF[4], bF[4];
#pragma unroll
            for (int i = 0; i < 4; ++i) aF[i] = *(const float4*)(AsC + (tr + 8*i)*32 + sA);
#pragma unroll
            for (int i = 0; i < 4; ++i) bF[i] = *(const float4*)(BsC + (k4+i)*128 + 4*tc);
#pragma unroll
            for (int i = 0; i < 4; ++i) {
                const float* ap = (const float*)&aF[i];
#pragma unroll
                for (int kk = 0; kk < 4; ++kk) {
                    float av = ap[kk];
                    const float* bp = (const float*)&bF[kk];
                    acc[i][0] += av*bp[0];
                    acc[i][1] += av*bp[1];
                    acc[i][2] += av*bp[2];
                    acc[i][3] += av*bp[3];
                }
            }
        }
        __syncthreads();                 // drains glds of chunk c+1 too
    }

    // ---- cell update: regroup gates via LDS (reuse Bs[0]) ----
    float* gl = &Bs[0][0];               // 32 x 128  [m][cc]
#pragma unroll
    for (int i = 0; i < 4; ++i) {
        float4 v; v.x = acc[i][0]; v.y = acc[i][1]; v.z = acc[i][2]; v.w = acc[i][3];
        *(float4*)(gl + (tr + 8*i)*128 + 4*tc) = v;
    }
    __syncthreads();
    float* hl = &As[0][0];               // 32 x 32
    for (int s = tid; s < 1024; s += 256) {
        int m = s >> 5, u = s & 31;
        int gb = (r0+m)*4096 + ubase + u;
        float gi = gl[m*128 + u +  0] + constG[gb +    0];
        float gf = gl[m*128 + u + 32] + constG[gb + 1024];
        float gg = gl[m*128 + u + 64] + constG[gb + 2048];
        float go = gl[m*128 + u + 96] + constG[gb + 3072];
        int ci = (r0+m)*1024 + ubase + u;
        float cO = cSt[ci];
        float cN = sigm(gf)*cO + sigm(gi)*tanhf(gg);
        float hN = sigm(go)*tanhf(cN);
        cSt[ci] = cN;
        hOut[ci] = hN;
        hl[s] = hN;
    }
    __syncthreads();

    // ---- fused split-K out-projection partial: hl(32x32) @ lin2t[ubase..+32][0..263) ----
    for (int s = tid; s < 32*66; s += 256) {
        int m = s / 66;
        int f0 = (s - m*66) * 4;
        const float* hrow = hl + m*32;
        float a0 = 0.f, a1 = 0.f, a2 = 0.f, a3 = 0.f;
        float* pp = partial + ((size_t)ut*256 + r0 + m)*Fsz + f0;
        if (f0 + 4 <= Fsz) {
#pragma unroll 8
            for (int k = 0; k < 32; ++k) {
                float hv = hrow[k];
                const float* bp = lin2t + (size_t)(ubase+k)*Fsz + f0;
                a0 += hv*bp[0]; a1 += hv*bp[1]; a2 += hv*bp[2]; a3 += hv*bp[3];
            }
            pp[0] = a0; pp[1] = a1; pp[2] = a2; pp[3] = a3;
        } else {                         // tail: f0 = 260 -> 3 elems
#pragma unroll 8
            for (int k = 0; k < 32; ++k) {
                float hv = hrow[k];
                const float* bp = lin2t + (size_t)(ubase+k)*Fsz + f0;
                a0 += hv*bp[0]; a1 += hv*bp[1]; a2 += hv*bp[2];
            }
            pp[0] = a0; pp[1] = a1; pp[2] = a2;
        }
    }
}

// ---------------- reduce partials + frame update -> d_out[:,t,:] ----------------
__global__ __launch_bounds__(256) void k2b(const float* __restrict__ framePrev, int frameStride,
                                           const float* __restrict__ partial,
                                           const float* __restrict__ l2b,
                                           float* __restrict__ outT, int outStride) {
    int idx = blockIdx.x*256 + threadIdx.x;
    if (idx >= 256*Fsz) return;
    int b = idx / Fsz, f = idx - b*Fsz;
    float s = framePrev[(size_t)b*frameStride + f] + l2b[f];
#pragma unroll
    for (int ut = 0; ut < 32; ++ut)
        s += partial[((size_t)ut*256 + b)*Fsz + f];
    outT[(size_t)b*outStride + f] = s;
}

extern "C" void kernel_launch(void* const* d_in, const int* in_sizes, int n_in,
                              void* d_out_v, int out_size, void* d_ws, size_t ws_size,
                              hipStream_t stream) {
    const float* motions = (const float*)d_in[0];
    const float* temb    = (const float*)d_in[1];
    const float* ltw     = (const float*)d_in[2];   // (512,768)
    const float* ltb     = (const float*)d_in[3];
    const float* l1w     = (const float*)d_in[4];   // (512,263)
    const float* l1b     = (const float*)d_in[5];
    const float* wih     = (const float*)d_in[6];   // (4096,1024)
    const float* whh     = (const float*)d_in[7];   // (4096,1024)
    const float* bih     = (const float*)d_in[8];
    const float* bhh     = (const float*)d_in[9];
    const float* l2w     = (const float*)d_in[10];  // (263,1024)
    const float* l2b     = (const float*)d_in[11];
    float* out = (float*)d_out_v;
    float* ws  = (float*)d_ws;
    if (ws_size < (size_t)WS_TOTAL * 4) return;   // need 46.2 MB scratch

    float* hbuf   = ws + WS_HBUF;
    float* cbuf   = ws + WS_CBUF;
    float* part   = ws + WS_PART;
    float* WihT   = ws + WS_WIHT;    // aliases hbuf/cbuf/part (precompute-only)
    float* WhhT   = ws + WS_WHHT;
    float* lin2t  = ws + WS_LIN2T;
    float* lin1t  = ws + WS_LIN1T;
    float* ltwT   = ws + WS_LTWT;
    float* textE  = ws + WS_TEXTE;
    float* Wcomb  = ws + WS_WCOMB;
    float* constG = ws + WS_CONSTG;
    float* biasG  = ws + WS_BIASG;

    dim3 blk(256);
    // ---- precompute (uses WihT region, then releases it to h/c/partial) ----
    tpose<<<dim3(32,128), blk, 0, stream>>>(wih, WihT, 4096, 1024);
    tpose<<<dim3(32,128), blk, 0, stream>>>(whh, WhhT, 4096, 1024);
    tpose<<<dim3(32,  9), blk, 0, stream>>>(l2w, lin2t, 263, 1024);
    tpose<<<dim3( 9, 16), blk, 0, stream>>>(l1w, lin1t, 512, 263);
    tpose<<<dim3(24, 16), blk, 0, stream>>>(ltw, ltwT, 512, 768);
    biasg_k<<<16, blk, 0, stream>>>(bih, bhh, l1b, WihT, biasG);
    // text_emb = temb @ ltw^T + ltb                      (256x512, K=768)
    nn_gemm<<<dim3( 8, 8), blk, 0, stream>>>(temb, ltwT, ltb, textE, 256, 256, 512, 768);
    // Wcomb = lin1^T @ wih[:, :512]^T  (rows 263..287=0)  (288x4096, K=512)
    nn_gemm<<<dim3(64, 9), blk, 0, stream>>>(lin1t, WihT, nullptr, Wcomb, 288, 263, 4096, 512);
    // constG = textE @ wih[:, 512:]^T + biasG             (256x4096, K=512)
    nn_gemm<<<dim3(64, 8), blk, 0, stream>>>(textE, WihT + (size_t)512*4096, biasG, constG,
                                             256, 256, 4096, 512);
    zero_f<<<3072, blk, 0, stream>>>(ws, 786432);   // h (both halves) + c = 0

    // ---- recurrence ----
    for (int t = 0; t < Tsz; ++t) {
        const float* frame = (t == 0) ? motions : (out + (size_t)(t-1)*Fsz);
        const float* hIn  = hbuf + (size_t)(t & 1) * 262144;
        float*       hOut = hbuf + (size_t)((t+1) & 1) * 262144;
        k1_step<<<dim3(32, 8), blk, 0, stream>>>(frame, TFs, Wcomb, hIn, WhhT, constG,
                                                 cbuf, hOut, lin2t, part);
        k2b<<<264, blk, 0, stream>>>(frame, TFs, part, l2b, out + (size_t)t*Fsz, TFs);
    }
}

// Round 5
// 6635.664 us; speedup vs baseline: 2.6054x; 2.6054x over previous
//
#include <hip/hip_runtime.h>
#include <math.h>

typedef _Float16 f16;
typedef __attribute__((ext_vector_type(8))) _Float16 f16x8;
typedef __attribute__((ext_vector_type(4))) float f32x4;

#define Bsz 256
#define Tsz 196
#define Fsz 263
#define TFs (Tsz*Fsz)   // 51548
#define SX  1312        // X row stride (288 frame-pad + 1024 h)
#define KCH 41          // 1312/32 k-chunks
#define LOSC 2048.0f
#define LOINV 0.00048828125f

// ---------------- ws layout (BYTE offsets) ----------------
#define OFF_WALLHI 0u            // packed f16 weights hi: 41*64*4096 B
#define OFF_WALLLO 10747904u     // lo (x2048)
// phase-1 alias: WihT fp32 (16.8MB) lives at 0, freed before pack_wall
#define OFF_R1     21495808u     // Wcomb fp32 (pre, 4.72MB) -> cSt fp32 (loop, 4MB)
#define OFF_R2     26214400u     // constG_j (pre, 4MB) -> X bufs + proj (loop)
#define OFF_XHI0   26214400u
#define OFF_XLO0   26886144u
#define OFF_XHI1   27557888u
#define OFF_XLO1   28229632u
#define OFF_PROJ   28901376u     // [4 ksplit][256][320] f32 = 1310720 B
#define OFF_CGP    30408704u     // constG permuted fp32 [256][4096] = 4MB
#define OFF_L2PH   34603008u     // lin2 packed hi: 32*5*4096 B
#define OFF_L2PL   35258368u
#define OFF_LIN1T  35913728u     // [263][512] f32
#define OFF_LTWT   36452352u     // [768][512] f32
#define OFF_TEXTE  38025216u     // [256][512] f32
#define OFF_BIASG  38549504u     // [4096] f32
#define OFF_WCT    38565888u     // WcombT fp32 [4096][288] = 4718592 B
#define WS_BYTES   43284480u

// ---------------- helpers ----------------
__device__ __forceinline__ void glds16(const void* g, void* l) {
    __builtin_amdgcn_global_load_lds(
        (const __attribute__((address_space(1))) void*)g,
        (__attribute__((address_space(3))) void*)l, 16, 0, 0);
}
__device__ __forceinline__ float sigm(float x) { return 1.f / (1.f + expf(-x)); }
// f16 hi/lo split; lo scaled by 2048 so it stays in f16-normal range.
__device__ __forceinline__ void split16(float x, f16& hi, f16& lo) {
    hi = (f16)x;
    lo = (f16)((x - (float)hi) * LOSC);
}
#define MFMA16(a,b,c) __builtin_amdgcn_mfma_f32_16x16x32_f16(a,b,c,0,0,0)

// ---------------- transpose: src[M][N] -> dst[N][M] ----------------
__global__ __launch_bounds__(256) void tpose(const float* __restrict__ src,
                                             float* __restrict__ dst, int M, int N) {
    __shared__ float tile[32][33];
    int bx = blockIdx.x, by = blockIdx.y;
    int tx = threadIdx.x & 31, ty = threadIdx.x >> 5;
#pragma unroll
    for (int i = 0; i < 4; ++i) {
        int row = by*32 + ty*4 + i, col = bx*32 + tx;
        tile[ty*4+i][tx] = (row < M && col < N) ? src[(size_t)row*N + col] : 0.f;
    }
    __syncthreads();
#pragma unroll
    for (int i = 0; i < 4; ++i) {
        int row = bx*32 + ty*4 + i, col = by*32 + tx;
        if (row < N && col < M) dst[(size_t)row*M + col] = tile[tx][ty*4+i];
    }
}

// ---------------- biasG_j[j] = bih+bhh + sum_e l1b[e]*wih[j][e] ----------------
__global__ __launch_bounds__(256) void biasg_k(const float* __restrict__ bih,
                                               const float* __restrict__ bhh,
                                               const float* __restrict__ l1b,
                                               const float* __restrict__ wih,
                                               float* __restrict__ bg) {
    int j = blockIdx.x*4 + (threadIdx.x >> 6);      // grid=1024 -> j<4096
    int l = threadIdx.x & 63;
    const float* wr = wih + (size_t)j*1024 + l*8;
    const float* lb = l1b + l*8;
    float s = 0.f;
#pragma unroll
    for (int e = 0; e < 8; ++e) s += lb[e] * wr[e];
#pragma unroll
    for (int off = 32; off; off >>= 1) s += __shfl_down(s, off, 64);
    if (l == 0) bg[j] = bih[j] + bhh[j] + s;
}

// ---------------- generic fp32 NN GEMM (precompute only) ----------------
__global__ __launch_bounds__(256) void nn_gemm(const float* __restrict__ A,
                                               const float* __restrict__ B,
                                               const float* __restrict__ bias,
                                               float* __restrict__ C,
                                               int M, int MA, int N, int K) {
    __shared__ float As[32][33];
    __shared__ float Bs[32][64];
    int tid = threadIdx.x;
    int r0 = blockIdx.y*32, c0 = blockIdx.x*64;
    int tr = tid >> 4, tc = tid & 15;
    float acc[2][4] = {};
    for (int k0 = 0; k0 < K; k0 += 32) {
        int m = tid >> 3, kb = (tid & 7)*4;
        int row = r0 + m;
#pragma unroll
        for (int i = 0; i < 4; ++i)
            As[m][kb+i] = (row < MA) ? A[(size_t)row*K + k0 + kb + i] : 0.f;
#pragma unroll
        for (int i = 0; i < 8; ++i) {
            int fi = i*256 + tid, kk = fi >> 6, cc = fi & 63;
            Bs[kk][cc] = B[(size_t)(k0+kk)*N + c0 + cc];
        }
        __syncthreads();
#pragma unroll
        for (int k = 0; k < 32; ++k) {
            float a0 = As[2*tr][k], a1 = As[2*tr+1][k];
            float b0 = Bs[k][4*tc], b1 = Bs[k][4*tc+1], b2 = Bs[k][4*tc+2], b3 = Bs[k][4*tc+3];
            acc[0][0]+=a0*b0; acc[0][1]+=a0*b1; acc[0][2]+=a0*b2; acc[0][3]+=a0*b3;
            acc[1][0]+=a1*b0; acc[1][1]+=a1*b1; acc[1][2]+=a1*b2; acc[1][3]+=a1*b3;
        }
        __syncthreads();
    }
#pragma unroll
    for (int i = 0; i < 2; ++i) {
        int row = r0 + 2*tr + i;
        if (row < M)
#pragma unroll
            for (int j = 0; j < 4; ++j) {
                int col = c0 + 4*tc + j;
                C[(size_t)row*N + col] = acc[i][j] + (bias ? bias[col] : 0.f);
            }
    }
}

// ---------------- pack Wall (hi/lo f16, glds-linear, swizzled) ----------------
// logical: Wall[k][p], k<288: WcombT[j][k]; k>=288: whh[j][k-288]; j = (p&3)*1024 + (p>>2)
__global__ __launch_bounds__(256) void pack_wall(const float* __restrict__ WcT,
                                                 const float* __restrict__ whh,
                                                 f16* __restrict__ Wh,
                                                 f16* __restrict__ Wl) {
    int q = threadIdx.x;
    int ct = blockIdx.x, kc = blockIdx.y;
    int k = kc*32 + (((q&3) ^ ((q>>3)&3)) << 3);
    int p = ct*64 + (q>>2);
    int j = (p&3)*1024 + (p>>2);
    size_t ob = ((size_t)(kc*64 + ct)*256 + q)*8;
#pragma unroll
    for (int e = 0; e < 8; ++e) {
        int kk = k + e;
        float v = (kk < 288) ? WcT[(size_t)j*288 + kk]
                             : whh[(size_t)j*1024 + (kk - 288)];
        split16(v, Wh[ob+e], Wl[ob+e]);
    }
}

// ---------------- pack lin2 (B[k=u][col=f] = l2w[f][u], pad f>=263 -> 0) ----------------
__global__ __launch_bounds__(256) void pack_lin2(const float* __restrict__ l2w,
                                                 f16* __restrict__ Lh,
                                                 f16* __restrict__ Ll) {
    int q = threadIdx.x;
    int ct = blockIdx.x, kc = blockIdx.y;   // ct<5, kc<32
    int k = kc*32 + (((q&3) ^ ((q>>3)&3)) << 3);
    int f = ct*64 + (q>>2);
    size_t ob = ((size_t)(kc*5 + ct)*256 + q)*8;
#pragma unroll
    for (int e = 0; e < 8; ++e) {
        float v = (f < Fsz) ? l2w[(size_t)f*1024 + k + e] : 0.f;
        split16(v, Lh[ob+e], Ll[ob+e]);
    }
}

// ---------------- permute constG to p = u*4+g layout ----------------
__global__ __launch_bounds__(256) void permute_cg(const float* __restrict__ cj,
                                                  float* __restrict__ cp) {
    int idx = blockIdx.x*256 + threadIdx.x;     // < 1048576
    int b = idx >> 12, p = idx & 4095;
    cp[idx] = cj[(b << 12) + ((p & 3) << 10) + (p >> 2)];
}

// ---------------- init: X0 (frame0 split + zero pads + h=0), cSt=0 ----------------
__global__ __launch_bounds__(256) void init_k(const float* __restrict__ motions,
                                              f16* __restrict__ Xh0,
                                              f16* __restrict__ Xl0,
                                              float* __restrict__ cSt) {
    int idx = blockIdx.x*256 + threadIdx.x;
    if (idx < 256*SX) {
        int b = idx / SX, k = idx - b*SX;
        float v = (k < Fsz) ? motions[(size_t)b*TFs + k] : 0.f;
        split16(v, Xh0[idx], Xl0[idx]);
    } else {
        int i2 = idx - 256*SX;
        if (i2 < 256*1024) cSt[i2] = 0.f;
    }
}

// ---------------- k1: gates GEMM (f16-split MFMA) + cell update ----------------
// D(256x4096,perm) = X(256x1312)@Wall(1312x4096) via hh + (hl+lh)/2048, + constG
// grid (64 ct, 4 rt), 256 thr = 4 waves, block tile 64 rows x 64 p-cols, wave 32x32.
__global__ __launch_bounds__(256) void k1_gates(
        const f16* __restrict__ Xh, const f16* __restrict__ Xl,
        const f16* __restrict__ Wh, const f16* __restrict__ Wl,
        const float* __restrict__ cgp, float* __restrict__ cSt,
        f16* __restrict__ XhN, f16* __restrict__ XlN)
{
    __shared__ __attribute__((aligned(16))) char smem[32768];
    const int tid = threadIdx.x;
    const int ct = blockIdx.x, rt = blockIdx.y;
    const int r0 = rt*64, p0 = ct*64;
    const int l = tid & 63;
    const int wr = (tid >> 7) & 1, wc = (tid >> 6) & 1;

    const int aswz = (((tid&3) ^ ((tid>>3)&3)) << 3);
    const f16* aSrcH = Xh + (size_t)(r0 + (tid>>2))*SX + aswz;
    const f16* aSrcL = Xl + (size_t)(r0 + (tid>>2))*SX + aswz;
    const f16* bSrcH = Wh + (size_t)ct*2048 + tid*8;
    const f16* bSrcL = Wl + (size_t)ct*2048 + tid*8;
    char* dA = smem + tid*16;
    char* dB = smem + 16384 + tid*16;

    int offA[2], offB[2];
#pragma unroll
    for (int R = 0; R < 2; ++R) {
        int g = l >> 4;
        int row = wr*32 + R*16 + (l & 15);
        offA[R] = row*64 + ((g ^ ((row>>1)&3)) & 3)*16;
        int col = wc*32 + R*16 + (l & 15);
        offB[R] = col*64 + ((g ^ ((col>>1)&3)) & 3)*16;
    }
    f32x4 hh[2][2] = {}, hl[2][2] = {}, lh[2][2] = {};

    // prologue stage chunk 0
    glds16(aSrcH, dA); glds16(aSrcL, dA + 4096);
    glds16(bSrcH, dB); glds16(bSrcL, dB + 4096);
    __syncthreads();

    for (int c = 0; c < KCH; ++c) {
        const int buf = c & 1;
        if (c + 1 < KCH) {
            const int nb = (buf ^ 1)*8192;
            glds16(aSrcH + (c+1)*32, dA + nb);
            glds16(aSrcL + (c+1)*32, dA + nb + 4096);
            glds16(bSrcH + (size_t)(c+1)*131072, dB + nb);
            glds16(bSrcL + (size_t)(c+1)*131072, dB + nb + 4096);
        }
        const char* At = smem + buf*8192;
        const char* Bt = smem + 16384 + buf*8192;
        f16x8 ah[2], al[2], bh[2], bl[2];
#pragma unroll
        for (int R = 0; R < 2; ++R) {
            ah[R] = *(const f16x8*)(At + offA[R]);
            al[R] = *(const f16x8*)(At + 4096 + offA[R]);
            bh[R] = *(const f16x8*)(Bt + offB[R]);
            bl[R] = *(const f16x8*)(Bt + 4096 + offB[R]);
        }
#pragma unroll
        for (int R = 0; R < 2; ++R)
#pragma unroll
            for (int C = 0; C < 2; ++C) {
                hh[R][C] = MFMA16(ah[R], bh[C], hh[R][C]);
                hl[R][C] = MFMA16(ah[R], bl[C], hl[R][C]);
                lh[R][C] = MFMA16(al[R], bh[C], lh[R][C]);
            }
        __syncthreads();    // drains glds of chunk c+1 too
    }

    // ---- D -> LDS (swizzled), then fused cell update ----
    float* gl = (float*)smem;   // 64x64 f32 = 16KB
#pragma unroll
    for (int R = 0; R < 2; ++R)
#pragma unroll
        for (int C = 0; C < 2; ++C) {
            f32x4 d = hh[R][C] + (hl[R][C] + lh[R][C]) * LOINV;
            int col = wc*32 + C*16 + (l & 15);
            int rb = wr*32 + R*16 + ((l >> 4) << 2);
#pragma unroll
            for (int j = 0; j < 4; ++j) {
                int r = rb + j;
                gl[r*64 + (col ^ ((r & 7) << 2))] = d[j];
            }
        }
    __syncthreads();
#pragma unroll
    for (int q = 0; q < 4; ++q) {
        int s = q*256 + tid;
        int m = s >> 4, u = s & 15;
        f32x4 gt = *(const f32x4*)(gl + m*64 + ((u << 2) ^ ((m & 7) << 2)));
        f32x4 cg = *(const f32x4*)(cgp + (size_t)(r0 + m)*4096 + p0 + (u << 2));
        float gi = gt.x + cg.x, gf = gt.y + cg.y, gg = gt.z + cg.z, go = gt.w + cg.w;
        int ug = ct*16 + u;
        int ci = (r0 + m)*1024 + ug;
        float cO = cSt[ci];
        float cN = sigm(gf)*cO + sigm(gi)*tanhf(gg);
        float hN = sigm(go)*tanhf(cN);
        cSt[ci] = cN;
        split16(hN, XhN[(size_t)(r0 + m)*SX + 288 + ug], XlN[(size_t)(r0 + m)*SX + 288 + ug]);
    }
}

// ---------------- k3: out-projection (f16-split MFMA, split-K x4) ----------------
// proj[ks][256][320] = h(256x1024 slice)@lin2pack(1024x320)
__global__ __launch_bounds__(256) void k3_proj(
        const f16* __restrict__ Xh, const f16* __restrict__ Xl,  // next-buf (holds h_t)
        const f16* __restrict__ Lh, const f16* __restrict__ Ll,
        float* __restrict__ proj)
{
    __shared__ __attribute__((aligned(16))) char smem[32768];
    const int tid = threadIdx.x;
    const int ct = blockIdx.x, rt = blockIdx.y, ks = blockIdx.z;
    const int r0 = rt*64;
    const int l = tid & 63;
    const int wr = (tid >> 7) & 1, wc = (tid >> 6) & 1;

    const int aswz = (((tid&3) ^ ((tid>>3)&3)) << 3);
    const f16* aSrcH = Xh + (size_t)(r0 + (tid>>2))*SX + 288 + aswz + ks*256;
    const f16* aSrcL = Xl + (size_t)(r0 + (tid>>2))*SX + 288 + aswz + ks*256;
    const f16* bSrcH = Lh + (size_t)(ks*8)*10240 + (size_t)ct*2048 + tid*8;
    const f16* bSrcL = Ll + (size_t)(ks*8)*10240 + (size_t)ct*2048 + tid*8;
    char* dA = smem + tid*16;
    char* dB = smem + 16384 + tid*16;

    int offA[2], offB[2];
#pragma unroll
    for (int R = 0; R < 2; ++R) {
        int g = l >> 4;
        int row = wr*32 + R*16 + (l & 15);
        offA[R] = row*64 + ((g ^ ((row>>1)&3)) & 3)*16;
        int col = wc*32 + R*16 + (l & 15);
        offB[R] = col*64 + ((g ^ ((col>>1)&3)) & 3)*16;
    }
    f32x4 hh[2][2] = {}, hl[2][2] = {}, lh[2][2] = {};

    glds16(aSrcH, dA); glds16(aSrcL, dA + 4096);
    glds16(bSrcH, dB); glds16(bSrcL, dB + 4096);
    __syncthreads();

    for (int c = 0; c < 8; ++c) {
        const int buf = c & 1;
        if (c + 1 < 8) {
            const int nb = (buf ^ 1)*8192;
            glds16(aSrcH + (c+1)*32, dA + nb);
            glds16(aSrcL + (c+1)*32, dA + nb + 4096);
            glds16(bSrcH + (size_t)(c+1)*10240, dB + nb);
            glds16(bSrcL + (size_t)(c+1)*10240, dB + nb + 4096);
        }
        const char* At = smem + buf*8192;
        const char* Bt = smem + 16384 + buf*8192;
        f16x8 ah[2], al[2], bh[2], bl[2];
#pragma unroll
        for (int R = 0; R < 2; ++R) {
            ah[R] = *(const f16x8*)(At + offA[R]);
            al[R] = *(const f16x8*)(At + 4096 + offA[R]);
            bh[R] = *(const f16x8*)(Bt + offB[R]);
            bl[R] = *(const f16x8*)(Bt + 4096 + offB[R]);
        }
#pragma unroll
        for (int R = 0; R < 2; ++R)
#pragma unroll
            for (int C = 0; C < 2; ++C) {
                hh[R][C] = MFMA16(ah[R], bh[C], hh[R][C]);
                hl[R][C] = MFMA16(ah[R], bl[C], hl[R][C]);
                lh[R][C] = MFMA16(al[R], bh[C], lh[R][C]);
            }
        __syncthreads();
    }
    float* pout = proj + (size_t)ks*81920;
#pragma unroll
    for (int R = 0; R < 2; ++R)
#pragma unroll
        for (int C = 0; C < 2; ++C) {
            f32x4 d = hh[R][C] + (hl[R][C] + lh[R][C]) * LOINV;
            int col = ct*64 + wc*32 + C*16 + (l & 15);
            int rb = r0 + wr*32 + R*16 + ((l >> 4) << 2);
#pragma unroll
            for (int j = 0; j < 4; ++j)
                pout[(size_t)(rb + j)*320 + col] = d[j];
        }
}

// ---------------- k2b: reduce proj + frame update + write X-next frame part ----------------
__global__ __launch_bounds__(256) void k2b(const float* __restrict__ fprev,
                                           const float* __restrict__ proj,
                                           const float* __restrict__ l2b,
                                           float* __restrict__ outT,
                                           f16* __restrict__ XhN,
                                           f16* __restrict__ XlN) {
    int idx = blockIdx.x*256 + threadIdx.x;
    if (idx >= 256*288) return;
    int b = idx / 288, f = idx - b*288;
    if (f < Fsz) {
        float v = fprev[(size_t)b*TFs + f] + l2b[f];
#pragma unroll
        for (int ks = 0; ks < 4; ++ks) v += proj[(size_t)ks*81920 + b*320 + f];
        outT[(size_t)b*TFs + f] = v;
        split16(v, XhN[(size_t)b*SX + f], XlN[(size_t)b*SX + f]);
    } else {
        XhN[(size_t)b*SX + f] = (f16)0.f;
        XlN[(size_t)b*SX + f] = (f16)0.f;
    }
}

extern "C" void kernel_launch(void* const* d_in, const int* in_sizes, int n_in,
                              void* d_out_v, int out_size, void* d_ws, size_t ws_size,
                              hipStream_t stream) {
    const float* motions = (const float*)d_in[0];
    const float* temb    = (const float*)d_in[1];
    const float* ltw     = (const float*)d_in[2];   // (512,768)
    const float* ltb     = (const float*)d_in[3];
    const float* l1w     = (const float*)d_in[4];   // (512,263)
    const float* l1b     = (const float*)d_in[5];
    const float* wih     = (const float*)d_in[6];   // (4096,1024)
    const float* whh     = (const float*)d_in[7];   // (4096,1024)
    const float* bih     = (const float*)d_in[8];
    const float* bhh     = (const float*)d_in[9];
    const float* l2w     = (const float*)d_in[10];  // (263,1024)
    const float* l2b     = (const float*)d_in[11];
    float* out = (float*)d_out_v;
    char* ws = (char*)d_ws;
    if (ws_size < (size_t)WS_BYTES) return;

    f16*   WallHi = (f16*)(ws + OFF_WALLHI);
    f16*   WallLo = (f16*)(ws + OFF_WALLLO);
    float* WihT   = (float*)(ws + OFF_WALLHI);    // phase-1 alias
    float* Wcomb  = (float*)(ws + OFF_R1);
    float* cSt    = (float*)(ws + OFF_R1);
    float* cgj    = (float*)(ws + OFF_R2);
    f16*   XhB[2] = { (f16*)(ws + OFF_XHI0), (f16*)(ws + OFF_XHI1) };
    f16*   XlB[2] = { (f16*)(ws + OFF_XLO0), (f16*)(ws + OFF_XLO1) };
    float* proj   = (float*)(ws + OFF_PROJ);
    float* cgp    = (float*)(ws + OFF_CGP);
    f16*   L2h    = (f16*)(ws + OFF_L2PH);
    f16*   L2l    = (f16*)(ws + OFF_L2PL);
    float* lin1t  = (float*)(ws + OFF_LIN1T);
    float* ltwT   = (float*)(ws + OFF_LTWT);
    float* textE  = (float*)(ws + OFF_TEXTE);
    float* biasG  = (float*)(ws + OFF_BIASG);
    float* WcT    = (float*)(ws + OFF_WCT);

    dim3 blk(256);
    // ---- precompute ----
    tpose<<<dim3(32,128), blk, 0, stream>>>(wih, WihT, 4096, 1024);
    tpose<<<dim3(24, 16), blk, 0, stream>>>(ltw, ltwT, 512, 768);
    tpose<<<dim3( 9, 16), blk, 0, stream>>>(l1w, lin1t, 512, 263);
    biasg_k<<<1024, blk, 0, stream>>>(bih, bhh, l1b, wih, biasG);
    nn_gemm<<<dim3( 8, 8), blk, 0, stream>>>(temb, ltwT, ltb, textE, 256, 256, 512, 768);
    nn_gemm<<<dim3(64, 9), blk, 0, stream>>>(lin1t, WihT, nullptr, Wcomb, 288, 263, 4096, 512);
    nn_gemm<<<dim3(64, 8), blk, 0, stream>>>(textE, WihT + (size_t)512*4096, biasG, cgj,
                                             256, 256, 4096, 512);
    tpose<<<dim3(128, 9), blk, 0, stream>>>(Wcomb, WcT, 288, 4096);
    permute_cg<<<4096, blk, 0, stream>>>(cgj, cgp);
    pack_wall<<<dim3(64, 41), blk, 0, stream>>>(WcT, whh, WallHi, WallLo);
    pack_lin2<<<dim3(5, 32), blk, 0, stream>>>(l2w, L2h, L2l);
    init_k<<<2336, blk, 0, stream>>>(motions, XhB[0], XlB[0], cSt);

    // ---- recurrence ----
    for (int t = 0; t < Tsz; ++t) {
        f16* Xhc = XhB[t & 1],      *Xlc = XlB[t & 1];
        f16* Xhn = XhB[(t+1) & 1],  *Xln = XlB[(t+1) & 1];
        const float* fprev = (t == 0) ? motions : (out + (size_t)(t-1)*Fsz);
        k1_gates<<<dim3(64, 4), blk, 0, stream>>>(Xhc, Xlc, WallHi, WallLo,
                                                  cgp, cSt, Xhn, Xln);
        k3_proj<<<dim3(5, 4, 4), blk, 0, stream>>>(Xhn, Xln, L2h, L2l, proj);
        k2b<<<288, blk, 0, stream>>>(fprev, proj, l2b, out + (size_t)t*Fsz, Xhn, Xln);
    }
}

// Round 6
// 4665.255 us; speedup vs baseline: 3.7059x; 1.4224x over previous
//
#include <hip/hip_runtime.h>
#include <math.h>

typedef _Float16 f16;
typedef __attribute__((ext_vector_type(8))) _Float16 f16x8;
typedef __attribute__((ext_vector_type(4))) float f32x4;

#define Bsz 256
#define Tsz 196
#define Fsz 263
#define TFs (Tsz*Fsz)   // 51548
#define SX  1312        // X row stride (288 frame-pad + 1024 h)
#define KCH 41          // 1312/32 k-chunks
#define LOSC 2048.0f
#define LOINV 0.00048828125f

// ---------------- ws layout (BYTE offsets) ----------------
#define OFF_WALLHI 0u            // packed f16 weights hi: 41*64*4096 B
#define OFF_WALLLO 10747904u     // lo (x2048)
// phase-1 alias: WihT fp32 (16.8MB) lives at 0, freed before pack_wall
#define OFF_R1     21495808u     // Wcomb fp32 (pre, 4.72MB) -> cSt fp32 (loop, 4MB)
#define OFF_R2     26214400u     // constG_j (pre, 4MB) -> X bufs + proj (loop)
#define OFF_XHI0   26214400u
#define OFF_XLO0   26886144u
#define OFF_XHI1   27557888u
#define OFF_XLO1   28229632u
#define OFF_PROJ   28901376u     // [4 ksplit][256][320] f32 = 1310720 B
#define OFF_CGP    30408704u     // constG permuted fp32 [256][4096] = 4MB
#define OFF_L2PH   34603008u     // lin2 packed hi: 32*5*4096 B
#define OFF_L2PL   35258368u
#define OFF_LIN1T  35913728u     // [263][512] f32
#define OFF_LTWT   36452352u     // [768][512] f32
#define OFF_TEXTE  38025216u     // [256][512] f32
#define OFF_BIASG  38549504u     // [4096] f32
#define OFF_WCT    38565888u     // WcombT fp32 [4096][288] = 4718592 B
#define WS_BYTES   43284480u

// ---------------- helpers ----------------
__device__ __forceinline__ void glds16(const void* g, void* l) {
    __builtin_amdgcn_global_load_lds(
        (const __attribute__((address_space(1))) void*)g,
        (__attribute__((address_space(3))) void*)l, 16, 0, 0);
}
__device__ __forceinline__ float sigm(float x) { return 1.f / (1.f + expf(-x)); }
// f16 hi/lo split; lo scaled by 2048 so it stays in f16-normal range.
__device__ __forceinline__ void split16(float x, f16& hi, f16& lo) {
    hi = (f16)x;
    lo = (f16)((x - (float)hi) * LOSC);
}
#define MFMA16(a,b,c) __builtin_amdgcn_mfma_f32_16x16x32_f16(a,b,c,0,0,0)

#define WAIT_BAR(N) do { \
    asm volatile("s_waitcnt vmcnt(" #N ")" ::: "memory"); \
    __builtin_amdgcn_s_barrier(); \
    __builtin_amdgcn_sched_barrier(0); \
} while (0)

// ---------------- transpose: src[M][N] -> dst[N][M] ----------------
__global__ __launch_bounds__(256) void tpose(const float* __restrict__ src,
                                             float* __restrict__ dst, int M, int N) {
    __shared__ float tile[32][33];
    int bx = blockIdx.x, by = blockIdx.y;
    int tx = threadIdx.x & 31, ty = threadIdx.x >> 5;
#pragma unroll
    for (int i = 0; i < 4; ++i) {
        int row = by*32 + ty*4 + i, col = bx*32 + tx;
        tile[ty*4+i][tx] = (row < M && col < N) ? src[(size_t)row*N + col] : 0.f;
    }
    __syncthreads();
#pragma unroll
    for (int i = 0; i < 4; ++i) {
        int row = bx*32 + ty*4 + i, col = by*32 + tx;
        if (row < N && col < M) dst[(size_t)row*M + col] = tile[tx][ty*4+i];
    }
}

// ---------------- biasG_j[j] = bih+bhh + sum_e l1b[e]*wih[j][e] ----------------
__global__ __launch_bounds__(256) void biasg_k(const float* __restrict__ bih,
                                               const float* __restrict__ bhh,
                                               const float* __restrict__ l1b,
                                               const float* __restrict__ wih,
                                               float* __restrict__ bg) {
    int j = blockIdx.x*4 + (threadIdx.x >> 6);      // grid=1024 -> j<4096
    int l = threadIdx.x & 63;
    const float* wr = wih + (size_t)j*1024 + l*8;
    const float* lb = l1b + l*8;
    float s = 0.f;
#pragma unroll
    for (int e = 0; e < 8; ++e) s += lb[e] * wr[e];
#pragma unroll
    for (int off = 32; off; off >>= 1) s += __shfl_down(s, off, 64);
    if (l == 0) bg[j] = bih[j] + bhh[j] + s;
}

// ---------------- generic fp32 NN GEMM (precompute only) ----------------
__global__ __launch_bounds__(256) void nn_gemm(const float* __restrict__ A,
                                               const float* __restrict__ B,
                                               const float* __restrict__ bias,
                                               float* __restrict__ C,
                                               int M, int MA, int N, int K) {
    __shared__ float As[32][33];
    __shared__ float Bs[32][64];
    int tid = threadIdx.x;
    int r0 = blockIdx.y*32, c0 = blockIdx.x*64;
    int tr = tid >> 4, tc = tid & 15;
    float acc[2][4] = {};
    for (int k0 = 0; k0 < K; k0 += 32) {
        int m = tid >> 3, kb = (tid & 7)*4;
        int row = r0 + m;
#pragma unroll
        for (int i = 0; i < 4; ++i)
            As[m][kb+i] = (row < MA) ? A[(size_t)row*K + k0 + kb + i] : 0.f;
#pragma unroll
        for (int i = 0; i < 8; ++i) {
            int fi = i*256 + tid, kk = fi >> 6, cc = fi & 63;
            Bs[kk][cc] = B[(size_t)(k0+kk)*N + c0 + cc];
        }
        __syncthreads();
#pragma unroll
        for (int k = 0; k < 32; ++k) {
            float a0 = As[2*tr][k], a1 = As[2*tr+1][k];
            float b0 = Bs[k][4*tc], b1 = Bs[k][4*tc+1], b2 = Bs[k][4*tc+2], b3 = Bs[k][4*tc+3];
            acc[0][0]+=a0*b0; acc[0][1]+=a0*b1; acc[0][2]+=a0*b2; acc[0][3]+=a0*b3;
            acc[1][0]+=a1*b0; acc[1][1]+=a1*b1; acc[1][2]+=a1*b2; acc[1][3]+=a1*b3;
        }
        __syncthreads();
    }
#pragma unroll
    for (int i = 0; i < 2; ++i) {
        int row = r0 + 2*tr + i;
        if (row < M)
#pragma unroll
            for (int j = 0; j < 4; ++j) {
                int col = c0 + 4*tc + j;
                C[(size_t)row*N + col] = acc[i][j] + (bias ? bias[col] : 0.f);
            }
    }
}

// ---------------- pack Wall (hi/lo f16, glds-linear, swizzled) ----------------
// logical: Wall[k][p], k<288: WcombT[j][k]; k>=288: whh[j][k-288]; j = (p&3)*1024 + (p>>2)
__global__ __launch_bounds__(256) void pack_wall(const float* __restrict__ WcT,
                                                 const float* __restrict__ whh,
                                                 f16* __restrict__ Wh,
                                                 f16* __restrict__ Wl) {
    int q = threadIdx.x;
    int ct = blockIdx.x, kc = blockIdx.y;
    int k = kc*32 + (((q&3) ^ ((q>>3)&3)) << 3);
    int p = ct*64 + (q>>2);
    int j = (p&3)*1024 + (p>>2);
    size_t ob = ((size_t)(kc*64 + ct)*256 + q)*8;
#pragma unroll
    for (int e = 0; e < 8; ++e) {
        int kk = k + e;
        float v = (kk < 288) ? WcT[(size_t)j*288 + kk]
                             : whh[(size_t)j*1024 + (kk - 288)];
        split16(v, Wh[ob+e], Wl[ob+e]);
    }
}

// ---------------- pack lin2 (B[k=u][col=f] = l2w[f][u], pad f>=263 -> 0) ----------------
__global__ __launch_bounds__(256) void pack_lin2(const float* __restrict__ l2w,
                                                 f16* __restrict__ Lh,
                                                 f16* __restrict__ Ll) {
    int q = threadIdx.x;
    int ct = blockIdx.x, kc = blockIdx.y;   // ct<5, kc<32
    int k = kc*32 + (((q&3) ^ ((q>>3)&3)) << 3);
    int f = ct*64 + (q>>2);
    size_t ob = ((size_t)(kc*5 + ct)*256 + q)*8;
#pragma unroll
    for (int e = 0; e < 8; ++e) {
        float v = (f < Fsz) ? l2w[(size_t)f*1024 + k + e] : 0.f;
        split16(v, Lh[ob+e], Ll[ob+e]);
    }
}

// ---------------- permute constG to p = u*4+g layout ----------------
__global__ __launch_bounds__(256) void permute_cg(const float* __restrict__ cj,
                                                  float* __restrict__ cp) {
    int idx = blockIdx.x*256 + threadIdx.x;     // < 1048576
    int b = idx >> 12, p = idx & 4095;
    cp[idx] = cj[(b << 12) + ((p & 3) << 10) + (p >> 2)];
}

// ---------------- init: X0 (frame0 split + zero pads + h=0), cSt=0 ----------------
__global__ __launch_bounds__(256) void init_k(const float* __restrict__ motions,
                                              f16* __restrict__ Xh0,
                                              f16* __restrict__ Xl0,
                                              float* __restrict__ cSt) {
    int idx = blockIdx.x*256 + threadIdx.x;
    if (idx < 256*SX) {
        int b = idx / SX, k = idx - b*SX;
        float v = (k < Fsz) ? motions[(size_t)b*TFs + k] : 0.f;
        split16(v, Xh0[idx], Xl0[idx]);
    } else {
        int i2 = idx - 256*SX;
        if (i2 < 256*1024) cSt[i2] = 0.f;
    }
}

// ---------------- k1: gates GEMM (f16-split MFMA) + cell update ----------------
// D(256x4096,perm) = X(256x1312)@Wall(1312x4096) via hh + (hl+lh)/2048, + constG
// grid (64 ct, 4 rt), 256 thr = 4 waves, block tile 64 rows x 64 p-cols, wave 32x32.
// Staging: 4 LDS buffers, depth-3 prefetch, counted vmcnt + raw s_barrier (T3/T4):
// per chunk c: wait vmcnt(8) [chunks c+1,c+2 stay in flight] -> barrier -> issue c+3
// -> ds_read+MFMA chunk c. Buffer reuse distance 4 makes the single barrier safe.
__global__ __launch_bounds__(256) void k1_gates(
        const f16* __restrict__ Xh, const f16* __restrict__ Xl,
        const f16* __restrict__ Wh, const f16* __restrict__ Wl,
        const float* __restrict__ cgp, float* __restrict__ cSt,
        f16* __restrict__ XhN, f16* __restrict__ XlN)
{
    __shared__ __attribute__((aligned(16))) char smem[65536];
    const int tid = threadIdx.x;
    const int ct = blockIdx.x, rt = blockIdx.y;
    const int r0 = rt*64, p0 = ct*64;
    const int l = tid & 63;
    const int wr = (tid >> 7) & 1, wc = (tid >> 6) & 1;

    const int aswz = (((tid&3) ^ ((tid>>3)&3)) << 3);
    const f16* aSrcH = Xh + (size_t)(r0 + (tid>>2))*SX + aswz;
    const f16* aSrcL = Xl + (size_t)(r0 + (tid>>2))*SX + aswz;
    const f16* bSrcH = Wh + (size_t)ct*2048 + tid*8;
    const f16* bSrcL = Wl + (size_t)ct*2048 + tid*8;

    int offA[2], offB[2];
#pragma unroll
    for (int R = 0; R < 2; ++R) {
        int g = l >> 4;
        int row = wr*32 + R*16 + (l & 15);
        offA[R] = row*64 + ((g ^ ((row>>1)&3)) & 3)*16;
        int col = wc*32 + R*16 + (l & 15);
        offB[R] = col*64 + ((g ^ ((col>>1)&3)) & 3)*16;
    }
    f32x4 hh[2][2] = {}, hl[2][2] = {}, lh[2][2] = {};

    auto issueLoads = [&](int c) {
        const int buf = c & 3;
        char* dA = smem + buf*8192 + tid*16;
        char* dB = smem + 32768 + buf*8192 + tid*16;
        glds16(aSrcH + c*32, dA);
        glds16(aSrcL + c*32, dA + 4096);
        glds16(bSrcH + (size_t)c*131072, dB);
        glds16(bSrcL + (size_t)c*131072, dB + 4096);
    };
    auto compute = [&](int c) {
        const char* At = smem + (c & 3)*8192;
        const char* Bt = smem + 32768 + (c & 3)*8192;
        f16x8 ah[2], al[2], bh[2], bl[2];
#pragma unroll
        for (int R = 0; R < 2; ++R) {
            ah[R] = *(const f16x8*)(At + offA[R]);
            al[R] = *(const f16x8*)(At + 4096 + offA[R]);
            bh[R] = *(const f16x8*)(Bt + offB[R]);
            bl[R] = *(const f16x8*)(Bt + 4096 + offB[R]);
        }
#pragma unroll
        for (int R = 0; R < 2; ++R)
#pragma unroll
            for (int C = 0; C < 2; ++C) {
                hh[R][C] = MFMA16(ah[R], bh[C], hh[R][C]);
                hl[R][C] = MFMA16(ah[R], bl[C], hl[R][C]);
                lh[R][C] = MFMA16(al[R], bh[C], lh[R][C]);
            }
    };

    issueLoads(0); issueLoads(1); issueLoads(2);
#pragma unroll 1
    for (int c = 0; c < KCH-3; ++c) {
        WAIT_BAR(8);
        issueLoads(c+3);
        compute(c);
    }
    WAIT_BAR(8); compute(KCH-3);
    WAIT_BAR(4); compute(KCH-2);
    WAIT_BAR(0); compute(KCH-1);
    __syncthreads();

    // ---- D -> LDS (swizzled), then fused cell update ----
    float* gl = (float*)smem;   // 64x64 f32 = 16KB
#pragma unroll
    for (int R = 0; R < 2; ++R)
#pragma unroll
        for (int C = 0; C < 2; ++C) {
            f32x4 d = hh[R][C] + (hl[R][C] + lh[R][C]) * LOINV;
            int col = wc*32 + C*16 + (l & 15);
            int rb = wr*32 + R*16 + ((l >> 4) << 2);
#pragma unroll
            for (int j = 0; j < 4; ++j) {
                int r = rb + j;
                gl[r*64 + (col ^ ((r & 7) << 2))] = d[j];
            }
        }
    __syncthreads();
#pragma unroll
    for (int q = 0; q < 4; ++q) {
        int s = q*256 + tid;
        int m = s >> 4, u = s & 15;
        f32x4 gt = *(const f32x4*)(gl + m*64 + ((u << 2) ^ ((m & 7) << 2)));
        f32x4 cg = *(const f32x4*)(cgp + (size_t)(r0 + m)*4096 + p0 + (u << 2));
        float gi = gt.x + cg.x, gf = gt.y + cg.y, gg = gt.z + cg.z, go = gt.w + cg.w;
        int ug = ct*16 + u;
        int ci = (r0 + m)*1024 + ug;
        float cO = cSt[ci];
        float cN = sigm(gf)*cO + sigm(gi)*tanhf(gg);
        float hN = sigm(go)*tanhf(cN);
        cSt[ci] = cN;
        split16(hN, XhN[(size_t)(r0 + m)*SX + 288 + ug], XlN[(size_t)(r0 + m)*SX + 288 + ug]);
    }
}

// ---------------- k3: out-projection (f16-split MFMA, split-K x4) ----------------
// proj[ks][256][320] = h(256x1024 slice)@lin2pack(1024x320). Same deep pipeline.
__global__ __launch_bounds__(256) void k3_proj(
        const f16* __restrict__ Xh, const f16* __restrict__ Xl,  // next-buf (holds h_t)
        const f16* __restrict__ Lh, const f16* __restrict__ Ll,
        float* __restrict__ proj)
{
    __shared__ __attribute__((aligned(16))) char smem[65536];
    const int tid = threadIdx.x;
    const int ct = blockIdx.x, rt = blockIdx.y, ks = blockIdx.z;
    const int r0 = rt*64;
    const int l = tid & 63;
    const int wr = (tid >> 7) & 1, wc = (tid >> 6) & 1;

    const int aswz = (((tid&3) ^ ((tid>>3)&3)) << 3);
    const f16* aSrcH = Xh + (size_t)(r0 + (tid>>2))*SX + 288 + aswz + ks*256;
    const f16* aSrcL = Xl + (size_t)(r0 + (tid>>2))*SX + 288 + aswz + ks*256;
    const f16* bSrcH = Lh + (size_t)(ks*8)*10240 + (size_t)ct*2048 + tid*8;
    const f16* bSrcL = Ll + (size_t)(ks*8)*10240 + (size_t)ct*2048 + tid*8;

    int offA[2], offB[2];
#pragma unroll
    for (int R = 0; R < 2; ++R) {
        int g = l >> 4;
        int row = wr*32 + R*16 + (l & 15);
        offA[R] = row*64 + ((g ^ ((row>>1)&3)) & 3)*16;
        int col = wc*32 + R*16 + (l & 15);
        offB[R] = col*64 + ((g ^ ((col>>1)&3)) & 3)*16;
    }
    f32x4 hh[2][2] = {}, hl[2][2] = {}, lh[2][2] = {};

    auto issueLoads = [&](int c) {
        const int buf = c & 3;
        char* dA = smem + buf*8192 + tid*16;
        char* dB = smem + 32768 + buf*8192 + tid*16;
        glds16(aSrcH + c*32, dA);
        glds16(aSrcL + c*32, dA + 4096);
        glds16(bSrcH + (size_t)c*10240, dB);
        glds16(bSrcL + (size_t)c*10240, dB + 4096);
    };
    auto compute = [&](int c) {
        const char* At = smem + (c & 3)*8192;
        const char* Bt = smem + 32768 + (c & 3)*8192;
        f16x8 ah[2], al[2], bh[2], bl[2];
#pragma unroll
        for (int R = 0; R < 2; ++R) {
            ah[R] = *(const f16x8*)(At + offA[R]);
            al[R] = *(const f16x8*)(At + 4096 + offA[R]);
            bh[R] = *(const f16x8*)(Bt + offB[R]);
            bl[R] = *(const f16x8*)(Bt + 4096 + offB[R]);
        }
#pragma unroll
        for (int R = 0; R < 2; ++R)
#pragma unroll
            for (int C = 0; C < 2; ++C) {
                hh[R][C] = MFMA16(ah[R], bh[C], hh[R][C]);
                hl[R][C] = MFMA16(ah[R], bl[C], hl[R][C]);
                lh[R][C] = MFMA16(al[R], bh[C], lh[R][C]);
            }
    };

    issueLoads(0); issueLoads(1); issueLoads(2);
#pragma unroll 1
    for (int c = 0; c < 5; ++c) {
        WAIT_BAR(8);
        issueLoads(c+3);
        compute(c);
    }
    WAIT_BAR(8); compute(5);
    WAIT_BAR(4); compute(6);
    WAIT_BAR(0); compute(7);

    float* pout = proj + (size_t)ks*81920;
#pragma unroll
    for (int R = 0; R < 2; ++R)
#pragma unroll
        for (int C = 0; C < 2; ++C) {
            f32x4 d = hh[R][C] + (hl[R][C] + lh[R][C]) * LOINV;
            int col = ct*64 + wc*32 + C*16 + (l & 15);
            int rb = r0 + wr*32 + R*16 + ((l >> 4) << 2);
#pragma unroll
            for (int j = 0; j < 4; ++j)
                pout[(size_t)(rb + j)*320 + col] = d[j];
        }
}

// ---------------- k2b: reduce proj + frame update + write X-next frame part ----------------
__global__ __launch_bounds__(256) void k2b(const float* __restrict__ fprev,
                                           const float* __restrict__ proj,
                                           const float* __restrict__ l2b,
                                           float* __restrict__ outT,
                                           f16* __restrict__ XhN,
                                           f16* __restrict__ XlN) {
    int idx = blockIdx.x*256 + threadIdx.x;
    if (idx >= 256*288) return;
    int b = idx / 288, f = idx - b*288;
    if (f < Fsz) {
        float v = fprev[(size_t)b*TFs + f] + l2b[f];
#pragma unroll
        for (int ks = 0; ks < 4; ++ks) v += proj[(size_t)ks*81920 + b*320 + f];
        outT[(size_t)b*TFs + f] = v;
        split16(v, XhN[(size_t)b*SX + f], XlN[(size_t)b*SX + f]);
    } else {
        XhN[(size_t)b*SX + f] = (f16)0.f;
        XlN[(size_t)b*SX + f] = (f16)0.f;
    }
}

extern "C" void kernel_launch(void* const* d_in, const int* in_sizes, int n_in,
                              void* d_out_v, int out_size, void* d_ws, size_t ws_size,
                              hipStream_t stream) {
    const float* motions = (const float*)d_in[0];
    const float* temb    = (const float*)d_in[1];
    const float* ltw     = (const float*)d_in[2];   // (512,768)
    const float* ltb     = (const float*)d_in[3];
    const float* l1w     = (const float*)d_in[4];   // (512,263)
    const float* l1b     = (const float*)d_in[5];
    const float* wih     = (const float*)d_in[6];   // (4096,1024)
    const float* whh     = (const float*)d_in[7];   // (4096,1024)
    const float* bih     = (const float*)d_in[8];
    const float* bhh     = (const float*)d_in[9];
    const float* l2w     = (const float*)d_in[10];  // (263,1024)
    const float* l2b     = (const float*)d_in[11];
    float* out = (float*)d_out_v;
    char* ws = (char*)d_ws;
    if (ws_size < (size_t)WS_BYTES) return;

    f16*   WallHi = (f16*)(ws + OFF_WALLHI);
    f16*   WallLo = (f16*)(ws + OFF_WALLLO);
    float* WihT   = (float*)(ws + OFF_WALLHI);    // phase-1 alias
    float* Wcomb  = (float*)(ws + OFF_R1);
    float* cSt    = (float*)(ws + OFF_R1);
    float* cgj    = (float*)(ws + OFF_R2);
    f16*   XhB[2] = { (f16*)(ws + OFF_XHI0), (f16*)(ws + OFF_XHI1) };
    f16*   XlB[2] = { (f16*)(ws + OFF_XLO0), (f16*)(ws + OFF_XLO1) };
    float* proj   = (float*)(ws + OFF_PROJ);
    float* cgp    = (float*)(ws + OFF_CGP);
    f16*   L2h    = (f16*)(ws + OFF_L2PH);
    f16*   L2l    = (f16*)(ws + OFF_L2PL);
    float* lin1t  = (float*)(ws + OFF_LIN1T);
    float* ltwT   = (float*)(ws + OFF_LTWT);
    float* textE  = (float*)(ws + OFF_TEXTE);
    float* biasG  = (float*)(ws + OFF_BIASG);
    float* WcT    = (float*)(ws + OFF_WCT);

    dim3 blk(256);
    // ---- precompute ----
    tpose<<<dim3(32,128), blk, 0, stream>>>(wih, WihT, 4096, 1024);
    tpose<<<dim3(24, 16), blk, 0, stream>>>(ltw, ltwT, 512, 768);
    tpose<<<dim3( 9, 16), blk, 0, stream>>>(l1w, lin1t, 512, 263);
    biasg_k<<<1024, blk, 0, stream>>>(bih, bhh, l1b, wih, biasG);
    nn_gemm<<<dim3( 8, 8), blk, 0, stream>>>(temb, ltwT, ltb, textE, 256, 256, 512, 768);
    nn_gemm<<<dim3(64, 9), blk, 0, stream>>>(lin1t, WihT, nullptr, Wcomb, 288, 263, 4096, 512);
    nn_gemm<<<dim3(64, 8), blk, 0, stream>>>(textE, WihT + (size_t)512*4096, biasG, cgj,
                                             256, 256, 4096, 512);
    tpose<<<dim3(128, 9), blk, 0, stream>>>(Wcomb, WcT, 288, 4096);
    permute_cg<<<4096, blk, 0, stream>>>(cgj, cgp);
    pack_wall<<<dim3(64, 41), blk, 0, stream>>>(WcT, whh, WallHi, WallLo);
    pack_lin2<<<dim3(5, 32), blk, 0, stream>>>(l2w, L2h, L2l);
    init_k<<<2336, blk, 0, stream>>>(motions, XhB[0], XlB[0], cSt);

    // ---- recurrence ----
    for (int t = 0; t < Tsz; ++t) {
        f16* Xhc = XhB[t & 1],      *Xlc = XlB[t & 1];
        f16* Xhn = XhB[(t+1) & 1],  *Xln = XlB[(t+1) & 1];
        const float* fprev = (t == 0) ? motions : (out + (size_t)(t-1)*Fsz);
        k1_gates<<<dim3(64, 4), blk, 0, stream>>>(Xhc, Xlc, WallHi, WallLo,
                                                  cgp, cSt, Xhn, Xln);
        k3_proj<<<dim3(5, 4, 4), blk, 0, stream>>>(Xhn, Xln, L2h, L2l, proj);
        k2b<<<288, blk, 0, stream>>>(fprev, proj, l2b, out + (size_t)t*Fsz, Xhn, Xln);
    }
}